// Round 6
// baseline (6052.216 us; speedup 1.0000x reference)
//
#include <hip/hip_runtime.h>
#include <hip/hip_cooperative_groups.h>
namespace cg = cooperative_groups;

// TransportKernel: loss = ||k_ZZ||_F^2 - 2||k_ZY||_F^2 + 0.01 * tr(Z^T (K_XX+1e-3 I)^{-1} Z)
// Cholesky A=LL^T; tr = ||L^{-1}Z||_F^2. ONE cooperative kernel (grid.sync between
// phases) does the whole factorization + forward solve: 79 syncs instead of ~130
// stream-serialized dispatches (~12us gap each, the measured round-4/5 bottleneck).
// Lazy-left-looking panels (no redundant TRSM work, round-5's mistake), rank-256
// trailing SYRK phases reading L in-place from padded A (round-5's Lp scratch had a
// 1KB power-of-2 stride -> channel aliasing, 665 vs 796 GB/s).

#define NN 4096
#define LDA 4100
#define OFF_W    ((size_t)NN*LDA)
#define OFF_LI   (OFF_W + (size_t)NN*4)     // 2 x 64x64 Linv^T buffers (parity)
#define OFF_ACC  (OFF_LI + 2*4096)

__device__ __forceinline__ float rdlane(float v, int l){
    return __int_as_float(__builtin_amdgcn_readlane(__float_as_int(v), l));
}

// stage 64x64 row-major tile (row stride `stride`) transposed into dst[t][r], stride 68
__device__ __forceinline__ void stageT(const float* __restrict__ src, float* __restrict__ dst,
                                       int tid){
#pragma unroll
    for (int it=0; it<4; ++it){
        int idx = tid + it*256, r = idx>>4, q = idx&15;
        float4 v = *(const float4*)(src + (size_t)r*LDA + q*4);
        dst[(q*4+0)*68+r]=v.x; dst[(q*4+1)*68+r]=v.y;
        dst[(q*4+2)*68+r]=v.z; dst[(q*4+3)*68+r]=v.w;
    }
}

__device__ __forceinline__ void gemm_acc(const float* __restrict__ Ab, const float* __restrict__ Bb,
                                         float acc[4][4], int tx, int ty){
#pragma unroll 8
    for (int t=0;t<64;t++){
        float4 a = *(const float4*)&Ab[t*68 + ty*4];
        float4 b = *(const float4*)&Bb[t*68 + tx*4];
        acc[0][0]+=a.x*b.x; acc[0][1]+=a.x*b.y; acc[0][2]+=a.x*b.z; acc[0][3]+=a.x*b.w;
        acc[1][0]+=a.y*b.x; acc[1][1]+=a.y*b.y; acc[1][2]+=a.y*b.z; acc[1][3]+=a.y*b.w;
        acc[2][0]+=a.z*b.x; acc[2][1]+=a.z*b.y; acc[2][2]+=a.z*b.z; acc[2][3]+=a.z*b.w;
        acc[3][0]+=a.w*b.x; acc[3][1]+=a.w*b.y; acc[3][2]+=a.w*b.z; acc[3][3]+=a.w*b.w;
    }
}

// Dm (=S_[0..], row-major stride 68) holds the updated diag block.
// chol64 (wave 0, registers) -> L to A(h,h) + LDS; blocked tri-inverse (256 thr)
// -> publish Linv^T to LTdst; forward-solve W rows h..h+63 via Linv.
__device__ void chol_inv_solve(float* S_, float* __restrict__ A, float* __restrict__ W,
                               float* __restrict__ LTdst, int h, int tid){
    float* Dm = S_;
    float* Li = S_ + 4352;
    float* Ws = S_ + 13056;
    float* Mt = S_ + 13312;
    __syncthreads();
    if (tid < 64){
        const int lane = tid;
        float row[64];
#pragma unroll
        for (int q=0;q<16;q++){
            float4 v = *(const float4*)&Dm[lane*68 + q*4];
            row[q*4]=v.x; row[q*4+1]=v.y; row[q*4+2]=v.z; row[q*4+3]=v.w;
        }
#pragma unroll
        for (int j=0;j<64;j++){
            float d  = rdlane(row[j], j);
            float sd = sqrtf(d);
            float iv = 1.0f/sd;
            float v  = (lane==j)? sd : row[j]*iv;
            row[j] = v;
#pragma unroll
            for (int c=j+1;c<64;c++) row[c] -= v*rdlane(v,c);
        }
#pragma unroll
        for (int q=0;q<16;q++){
            float4 v = make_float4(row[q*4],row[q*4+1],row[q*4+2],row[q*4+3]);
            *(float4*)(A + (size_t)(h+lane)*LDA + h + q*4) = v;
            *(float4*)&Dm[lane*68 + q*4] = v;
        }
    }
    __syncthreads();
    for (int idx=tid; idx<4096; idx+=256){
        int r=idx>>6, c=idx&63;
        if (r<c) Li[r*68+c]=0.f;
    }
    __syncthreads();
    {   // 16x16 diag-block inverses: 4 blocks x 16 cols x 4 lanes
        const int d = tid>>6, cc=(tid>>2)&15, g2=tid&3;
        const int c = d*16+cc, hi=(d+1)*16;
        for (int jj=c; jj<hi; ++jj){
            float part=0.f;
            for (int t=c+g2; t<jj; t+=4) part += Dm[jj*68+t]*Li[t*68+c];
            part += __shfl_xor(part,1);
            part += __shfl_xor(part,2);
            float x = ((jj==c)?1.f:0.f) - part;
            x /= Dm[jj*68+jj];
            if (g2==0) Li[jj*68+c]=x;
        }
    }
    __syncthreads();
    {   // off-diag 16x16 blocks by distance
        const int r16=tid>>4, c16=tid&15;
        for (int sd2=1; sd2<4; ++sd2){
            for (int bc=0; bc+sd2<4; ++bc){
                const int br=bc+sd2;
                float m=0.f;
                for (int k=bc;k<br;++k)
#pragma unroll 4
                    for (int t2=0;t2<16;t2++)
                        m += Dm[(16*br+r16)*68+16*k+t2]*Li[(16*k+t2)*68+16*bc+c16];
                Mt[r16*17+c16]=m;
                __syncthreads();
                float x=0.f;
#pragma unroll 4
                for (int t=0;t<16;t++)
                    x += Li[(16*br+r16)*68+16*br+t]*Mt[t*17+c16];
                __syncthreads();
                Li[(16*br+r16)*68+16*bc+c16] = -x;
                __syncthreads();
            }
        }
    }
    for (int idx=tid; idx<4096; idx+=256){
        int t=idx>>6, c=idx&63;
        LTdst[idx] = Li[c*68+t];          // [t][c] = Linv(c,t)
    }
    if (tid<64) *(float4*)&Ws[tid*4] = *(const float4*)(W + (size_t)(h+tid)*4);
    __syncthreads();
    {
        int i=tid>>2, c=tid&3;
        float s=0.f;
        for (int j=0;j<=i;j++) s += Li[i*68+j]*Ws[j*4+c];
        W[(size_t)(h+i)*4+c] = s;
    }
}

// ------------------------------------------------------------------
__device__ void syrk_tile(float* __restrict__ A, float* S_, int k0, int base, int t2,
                          int tid, int tx, int ty){
    float* Sa = S_;
    float* Sb = S_+4224;
    int bi = (int)((sqrtf(8.f*(float)t2+1.f)-1.f)*0.5f);
    while ((bi+1)*(bi+2)/2 <= t2) ++bi;
    while (bi*(bi+1)/2 > t2) --bi;
    const int bj = t2 - bi*(bi+1)/2;
    const int r0 = base + bi*128, c0 = base + bj*128;
    const bool dg = (bi==bj);
    const float* Sbp = dg ? Sa : Sb;
    int row_[4], q_[4];
#pragma unroll
    for (int it=0;it<4;++it){ int ix=tid+it*256; row_[it]=ix>>3; q_[it]=ix&7; }
    float4 ra[4], rb[4];
#pragma unroll
    for (int it=0;it<4;++it){
        ra[it] = *(const float4*)(A + (size_t)(r0+row_[it])*LDA + k0 + q_[it]*4);
        if (!dg) rb[it] = *(const float4*)(A + (size_t)(c0+row_[it])*LDA + k0 + q_[it]*4);
    }
    float acc[8][8]={};
    for (int kk=0;kk<8;++kk){
        __syncthreads();
#pragma unroll
        for (int it=0;it<4;++it){
            Sa[(q_[it]*4+0)*132+row_[it]]=ra[it].x; Sa[(q_[it]*4+1)*132+row_[it]]=ra[it].y;
            Sa[(q_[it]*4+2)*132+row_[it]]=ra[it].z; Sa[(q_[it]*4+3)*132+row_[it]]=ra[it].w;
            if (!dg){
                Sb[(q_[it]*4+0)*132+row_[it]]=rb[it].x; Sb[(q_[it]*4+1)*132+row_[it]]=rb[it].y;
                Sb[(q_[it]*4+2)*132+row_[it]]=rb[it].z; Sb[(q_[it]*4+3)*132+row_[it]]=rb[it].w;
            }
        }
        __syncthreads();
        if (kk < 7){
            const int kb = k0 + (kk+1)*32;
#pragma unroll
            for (int it=0;it<4;++it){
                ra[it] = *(const float4*)(A + (size_t)(r0+row_[it])*LDA + kb + q_[it]*4);
                if (!dg) rb[it] = *(const float4*)(A + (size_t)(c0+row_[it])*LDA + kb + q_[it]*4);
            }
        }
#pragma unroll 4
        for (int t=0;t<32;++t){
            float4 a0 = *(const float4*)&Sa[t*132 + ty*8];
            float4 a1 = *(const float4*)&Sa[t*132 + ty*8 + 4];
            float4 b0 = *(const float4*)&Sbp[t*132 + tx*4];
            float4 b1 = *(const float4*)&Sbp[t*132 + 64 + tx*4];
            float av[8]={a0.x,a0.y,a0.z,a0.w,a1.x,a1.y,a1.z,a1.w};
            float bv[8]={b0.x,b0.y,b0.z,b0.w,b1.x,b1.y,b1.z,b1.w};
#pragma unroll
            for (int ii=0;ii<8;ii++)
#pragma unroll
                for (int jj=0;jj<8;jj++) acc[ii][jj] += av[ii]*bv[jj];
        }
    }
#pragma unroll
    for (int ii=0;ii<8;ii++){
        const int r = r0 + ty*8 + ii;
        const int c1 = c0 + tx*4;
        const int c2 = c0 + 64 + tx*4;
        if (!(r < base+64 && c1 < base+64)){
            float* p = A + (size_t)r*LDA + c1;
            float4 cv = *(float4*)p;
            cv.x-=acc[ii][0]; cv.y-=acc[ii][1]; cv.z-=acc[ii][2]; cv.w-=acc[ii][3];
            *(float4*)p = cv;
        }
        if (!(r < base+64 && c2 < base+64)){
            float* p = A + (size_t)r*LDA + c2;
            float4 cv = *(float4*)p;
            cv.x-=acc[ii][4]; cv.y-=acc[ii][5]; cv.z-=acc[ii][6]; cv.w-=acc[ii][7];
            *(float4*)p = cv;
        }
    }
}

// ------------------------------------------------------------------
__global__ __launch_bounds__(256,2) void k_coop(float* __restrict__ A, float* __restrict__ W,
                                                float* __restrict__ LinvTg){
    cg::grid_group grid = cg::this_grid();
    __shared__ float S_[13584];
    const int tid = threadIdx.x;
    const int bid = blockIdx.x;
    const int tx = tid&15, ty = tid>>4;
    float* Ab = S_;
    float* Bb = S_+4352;
    float* Iv = S_+8704;
    float* Ws = S_+13056;

    // phase -1: chol of head block (0,0)
    if (bid==0){
#pragma unroll
        for (int it=0; it<4; ++it){
            int idx=tid+it*256, r=idx>>4, q=idx&15;
            *(float4*)&Ab[r*68+q*4] = *(const float4*)(A + (size_t)r*LDA + q*4);
        }
        chol_inv_solve(S_, A, W, LinvTg, 0, tid);
    }
    grid.sync();

    for (int s=0; s<63; ++s){
        const int S = s>>2;
        const int scol = s*64;
        const int nrt = 63 - s;
        if (bid < nrt){
            const int r = s+1+bid;
            const int r64 = r*64;
            const float* LT = LinvTg + ((s&1)<<12);
#pragma unroll
            for (int it=0;it<4;++it){
                int idx=tid+it*256, t=idx>>4, q=idx&15;
                *(float4*)&Iv[t*68+q*4] = *(const float4*)(LT + t*64 + q*4);
            }
            if (tid<64) *(float4*)&Ws[tid*4] = *(const float4*)(W + (size_t)(scol+tid)*4);
            float acc[4][4]={};
            for (int p=4*S; p<s; ++p){
                __syncthreads();
                stageT(A + (size_t)r64*LDA + p*64, Ab, tid);
                stageT(A + (size_t)scol*LDA + p*64, Bb, tid);
                __syncthreads();
                gemm_acc(Ab, Bb, acc, tx, ty);
            }
            __syncthreads();
            stageT(A + (size_t)r64*LDA + scol, Ab, tid);
            __syncthreads();
#pragma unroll
            for (int ii=0;ii<4;ii++)
#pragma unroll
                for (int jj=0;jj<4;jj++)
                    Ab[(tx*4+jj)*68 + ty*4+ii] -= acc[ii][jj];   // own cells only
            __syncthreads();
            float l[4][4]={};
            gemm_acc(Ab, Iv, l, tx, ty);
#pragma unroll
            for (int ii=0;ii<4;ii++)
                *(float4*)(A + (size_t)(r64+ty*4+ii)*LDA + scol + tx*4) =
                    make_float4(l[ii][0],l[ii][1],l[ii][2],l[ii][3]);
            __syncthreads();
#pragma unroll
            for (int ii=0;ii<4;ii++)
#pragma unroll
                for (int jj=0;jj<4;jj++)
                    Bb[(tx*4+jj)*68 + ty*4+ii] = l[ii][jj];      // LnT
            __syncthreads();
            {   // W update for rows r
                int i=tid>>2, c=tid&3;
                float s2=0.f;
#pragma unroll 16
                for (int j=0;j<64;j++) s2 += Bb[j*68+i]*Ws[j*4+c];
                float* wp = W + (size_t)(r64+i)*4 + c;
                *wp -= s2;
            }
            if (r <= 4*S+3){
                __syncthreads();
                float dd[4][4]={};
                gemm_acc(Bb, Bb, dd, tx, ty);
                if (r == s+1){
                    // pipeline: updated diag -> LDS row-major, chol+inv+publish+solve
#pragma unroll
                    for (int ii=0;ii<4;ii++){
                        float4 c4 = *(const float4*)(A + (size_t)(r64+ty*4+ii)*LDA + r64 + tx*4);
                        c4.x-=dd[ii][0]; c4.y-=dd[ii][1]; c4.z-=dd[ii][2]; c4.w-=dd[ii][3];
                        *(float4*)&Ab[(ty*4+ii)*68 + tx*4] = c4;
                    }
                    chol_inv_solve(S_, A, W, LinvTg + (((s+1)&1)<<12), r64, tid);
                } else {
#pragma unroll
                    for (int ii=0;ii<4;ii++){
                        float* p = A + (size_t)(r64+ty*4+ii)*LDA + r64 + tx*4;
                        float4 c4 = *(float4*)p;
                        c4.x-=dd[ii][0]; c4.y-=dd[ii][1]; c4.z-=dd[ii][2]; c4.w-=dd[ii][3];
                        *(float4*)p = c4;
                    }
                }
            }
        }
        grid.sync();
        if ((s&3)==3){
            const int k0 = S*256, base = k0+256;
            const int T2 = (4096-base)>>7;
            const int nT2 = T2*(T2+1)/2;
            if (bid==0){
                // next head: rank-256 update + chol + inv + W-solve (publishes buf 0)
                float acc[4][4]={};
                for (int kk=0;kk<4;++kk){
                    __syncthreads();
                    stageT(A + (size_t)base*LDA + k0 + kk*64, Bb, tid);
                    __syncthreads();
                    gemm_acc(Bb, Bb, acc, tx, ty);
                }
                __syncthreads();
#pragma unroll
                for (int ii=0;ii<4;ii++){
                    float4 c4 = *(const float4*)(A + (size_t)(base+ty*4+ii)*LDA + base + tx*4);
                    c4.x-=acc[ii][0]; c4.y-=acc[ii][1]; c4.z-=acc[ii][2]; c4.w-=acc[ii][3];
                    *(float4*)&Ab[(ty*4+ii)*68 + tx*4] = c4;
                }
                chol_inv_solve(S_, A, W, LinvTg, base, tid);
            } else {
                const int stride = (int)gridDim.x - 1;
                for (int t2=bid-1; t2<nT2; t2+=stride)
                    syrk_tile(A, S_, k0, base, t2, tid, tx, ty);
            }
            grid.sync();
        }
    }
}

// ------------------------------------------------------------------
__global__ void k_build_A(const float* __restrict__ X, float* __restrict__ A){
    const int i  = blockIdx.y;
    const int j0 = (blockIdx.x*256 + threadIdx.x)*4;
    const float4 xi = *(const float4*)(X + (size_t)i*4);
    float out[4];
#pragma unroll
    for (int s=0;s<4;s++){
        const float4 xj = *(const float4*)(X + (size_t)(j0+s)*4);
        float d0=xi.x-xj.x, d1=xi.y-xj.y, d2=xi.z-xj.z, d3=xi.w-xj.w;
        float sq = d0*d0+d1*d1+d2*d2+d3*d3;
        float v  = __expf(-0.5f*sq);
        if (i == j0+s) v += 0.001f;
        out[s]=v;
    }
    *(float4*)(A + (size_t)i*LDA + j0) = make_float4(out[0],out[1],out[2],out[3]);
}

__global__ void k_init(const float* __restrict__ Z, float* __restrict__ W,
                       double* __restrict__ acc){
    const int i = blockIdx.x*256+threadIdx.x;
    ((float4*)W)[i] = ((const float4*)Z)[i];
    if (blockIdx.x==0 && threadIdx.x==0) acc[0]=0.0;
}

__global__ void k_lossfit(const float* __restrict__ Z, const float* __restrict__ Y,
                          double* __restrict__ acc){
    const int tid=threadIdx.x;
    const int i0=blockIdx.x*8;
    double s=0.0;
    for (int ii=0;ii<8;ii++){
        const float4 zi = *(const float4*)(Z + (size_t)(i0+ii)*4);
        for (int j=tid;j<NN;j+=256){
            float4 zj = *(const float4*)(Z + (size_t)j*4);
            float4 yj = *(const float4*)(Y + (size_t)j*4);
            float d0=zi.x-zj.x, d1=zi.y-zj.y, d2=zi.z-zj.z, d3=zi.w-zj.w;
            float dzz = d0*d0+d1*d1+d2*d2+d3*d3;
            d0=zi.x-yj.x; d1=zi.y-yj.y; d2=zi.z-yj.z; d3=zi.w-yj.w;
            float dzy = d0*d0+d1*d1+d2*d2+d3*d3;
            s += (double)(__expf(-dzz) - 2.f*__expf(-dzy));
        }
    }
    for (int o=32;o;o>>=1) s += __shfl_down(s,o);
    __shared__ double ps[4];
    if ((tid&63)==0) ps[tid>>6]=s;
    __syncthreads();
    if (tid==0) atomicAdd(acc, ps[0]+ps[1]+ps[2]+ps[3]);
}

__global__ void k_finish(const float* __restrict__ W, const double* __restrict__ acc,
                         float* __restrict__ out){
    const int tid=threadIdx.x;
    double s=0.0;
    for (int r=tid;r<NN;r+=256){
        float4 v=*(const float4*)(W+(size_t)r*4);
        s += (double)v.x*v.x+(double)v.y*v.y+(double)v.z*v.z+(double)v.w*v.w;
    }
    for (int o=32;o;o>>=1) s += __shfl_down(s,o);
    __shared__ double ps[4];
    if ((tid&63)==0) ps[tid>>6]=s;
    __syncthreads();
    if (tid==0) out[0] = (float)(acc[0] + 0.01*(ps[0]+ps[1]+ps[2]+ps[3]));
}

// ------------------------------------------------------------------
extern "C" void kernel_launch(void* const* d_in, const int* in_sizes, int n_in,
                              void* d_out, int out_size, void* d_ws, size_t ws_size,
                              hipStream_t stream){
    const float* X=(const float*)d_in[0];
    const float* Y=(const float*)d_in[1];
    const float* Z=(const float*)d_in[2];
    float* ws   = (float*)d_ws;
    float* A    = ws;
    float* W    = ws + OFF_W;
    float* Li   = ws + OFF_LI;
    double* acc = (double*)(ws + OFF_ACC);

    if (ws_size < (OFF_ACC+4)*sizeof(float)) return;  // loud failure: out stays poisoned

    k_init   <<<16,256,0,stream>>>(Z, W, acc);
    k_build_A<<<dim3(4,NN),256,0,stream>>>(X, A);
    k_lossfit<<<512,256,0,stream>>>(Z, Y, acc);

    int nb = 0;
    hipOccupancyMaxActiveBlocksPerMultiprocessor(&nb, (const void*)k_coop, 256, 0);
    if (nb < 1) nb = 1;
    int gridc = nb*256; if (gridc > 512) gridc = 512;
    void* args[] = { (void*)&A, (void*)&W, (void*)&Li };
    hipLaunchCooperativeKernel((const void*)k_coop, dim3(gridc), dim3(256), args, 0, stream);

    k_finish<<<1,256,0,stream>>>(W, acc, (float*)d_out);
}